// Round 2
// baseline (747.568 us; speedup 1.0000x reference)
//
#include <hip/hip_runtime.h>

// ---------------------------------------------------------------------------
// G_CAM_Module: out = gamma * (GA @ x) + x, where GA comes from a chain of
// softmaxed 64x64 Gram matrices of x and g.
//
// Decomposition:
//   A) gram_kernel : ex[b] = x_b @ x_b^T, eg[b] = g_b @ g_b^T  (f16 dot2, f32 acc)
//   B) chain_kernel: softmax(ex), softmax(eg), GE = A1@A2, GEN = rowmax-GE,
//                    GA = softmax(GEN), M = gamma*GA + I      (tiny, fp32)
//   C) apply_kernel: out[b] = M[b] @ x_b                       (fp32 VALU)
// ---------------------------------------------------------------------------

typedef _Float16 h2 __attribute__((ext_vector_type(2)));
typedef __fp16   p2 __attribute__((ext_vector_type(2)));   // cvt_pkrtz result type
typedef float    f4 __attribute__((ext_vector_type(4)));
typedef unsigned int u4 __attribute__((ext_vector_type(4)));

#define NB 16
#define NC 64
#define NPIX 65536
#define GRAM_CHUNK 1024        // pixels per block
#define PASS_PX 128            // pixels per LDS pass
#define NPASS (GRAM_CHUNK / PASS_PX)   // 8
#define ROW_H 136              // halves per LDS row (128 data + 8 pad)
#define LDS_H (63 * ROW_H + 7 * 8 + ROW_H)  // halves per matrix

__device__ __forceinline__ int rowbase_h(int c) {
    // +16B gap every 8 rows: rows 8 apart land on distinct banks for the
    // 8x8-tile fragment reads (bank = 4*t + const, t=0..7 -> conflict-free).
    return c * ROW_H + (c >> 3) * 8;
}

__device__ __forceinline__ unsigned int pk(float a, float b) {
    p2 v = __builtin_amdgcn_cvt_pkrtz(a, b);
    return __builtin_bit_cast(unsigned int, v);
}

// ---- Kernel A: Gram matrices --------------------------------------------
// grid (64, 16): blockIdx.x = 1024-px chunk, blockIdx.y = batch. 256 threads.
// Thread roles: m = x/g matrix, hlf = pixel-half, 8x8 channel tile (ti,tj).
__global__ __launch_bounds__(256, 2) void gram_kernel(
    const float* __restrict__ x, const float* __restrict__ g,
    float* __restrict__ ex, float* __restrict__ eg)
{
    __shared__ __align__(16) _Float16 lds[2 * LDS_H];
    _Float16* xs = lds;
    _Float16* gs = lds + LDS_H;

    const int tid = threadIdx.x;
    const int b = blockIdx.y;
    const size_t cbase = (size_t)b * NC * NPIX + (size_t)blockIdx.x * GRAM_CHUNK;

    const int m   = tid >> 7;        // 0: x-gram, 1: g-gram
    const int hlf = (tid >> 6) & 1;  // pixel-group parity
    const int t   = tid & 63;
    const int ti  = t >> 3;          // 8x8 tile row
    const int tj  = t & 7;           // 8x8 tile col
    const _Float16* mybuf = m ? gs : xs;

    float acc[8][8];
    #pragma unroll
    for (int i = 0; i < 8; ++i)
        #pragma unroll
        for (int j = 0; j < 8; ++j) acc[i][j] = 0.f;

    for (int pass = 0; pass < NPASS; ++pass) {
        const size_t pbase = cbase + (size_t)pass * PASS_PX;
        // ---- stage 64ch x 128px of x and g into LDS as f16 ----
        #pragma unroll
        for (int it = 0; it < 8; ++it) {
            int e = it * 256 + tid;       // 0..2047
            int c = e >> 5;               // channel
            int q = e & 31;               // float4 index within 128 px
            f4 vx = *(const f4*)(x + pbase + (size_t)c * NPIX + q * 4);
            f4 vg = *(const f4*)(g + pbase + (size_t)c * NPIX + q * 4);
            u4 hx = { pk(vx.x, vx.y), pk(vx.z, vx.w), 0u, 0u };
            u4 hg = { pk(vg.x, vg.y), pk(vg.z, vg.w), 0u, 0u };
            int off = rowbase_h(c) + q * 4;
            *reinterpret_cast<unsigned long long*>(&xs[off]) =
                (unsigned long long)hx.x | ((unsigned long long)hx.y << 32);
            *reinterpret_cast<unsigned long long*>(&gs[off]) =
                (unsigned long long)hg.x | ((unsigned long long)hg.y << 32);
        }
        __syncthreads();

        // ---- accumulate 8x8 tile via v_dot2_f32_f16 ----
        #pragma unroll
        for (int it = 0; it < 8; ++it) {
            int pg = it * 2 + hlf;        // 4-pair group (8 px)
            int colh = pg * 8;            // halves into the row
            h2 pa[8][4];
            #pragma unroll
            for (int i = 0; i < 8; ++i) {
                u4 u = *reinterpret_cast<const u4*>(&mybuf[rowbase_h(ti * 8 + i) + colh]);
                pa[i][0] = __builtin_bit_cast(h2, u.x);
                pa[i][1] = __builtin_bit_cast(h2, u.y);
                pa[i][2] = __builtin_bit_cast(h2, u.z);
                pa[i][3] = __builtin_bit_cast(h2, u.w);
            }
            #pragma unroll
            for (int j = 0; j < 8; ++j) {
                u4 u = *reinterpret_cast<const u4*>(&mybuf[rowbase_h(tj * 8 + j) + colh]);
                h2 q0 = __builtin_bit_cast(h2, u.x);
                h2 q1 = __builtin_bit_cast(h2, u.y);
                h2 q2 = __builtin_bit_cast(h2, u.z);
                h2 q3 = __builtin_bit_cast(h2, u.w);
                #pragma unroll
                for (int i = 0; i < 8; ++i) {
                    acc[i][j] = __builtin_amdgcn_fdot2(pa[i][0], q0, acc[i][j], false);
                    acc[i][j] = __builtin_amdgcn_fdot2(pa[i][1], q1, acc[i][j], false);
                    acc[i][j] = __builtin_amdgcn_fdot2(pa[i][2], q2, acc[i][j], false);
                    acc[i][j] = __builtin_amdgcn_fdot2(pa[i][3], q3, acc[i][j], false);
                }
            }
        }
        __syncthreads();
    }

    float* eout = (m ? eg : ex) + b * (NC * NC);
    #pragma unroll
    for (int i = 0; i < 8; ++i)
        #pragma unroll
        for (int j = 0; j < 8; ++j)
            atomicAdd(&eout[(ti * 8 + i) * NC + (tj * 8 + j)], acc[i][j]);
}

// ---- Kernel B: softmax chain -> M = gamma*GA + I -------------------------
// grid 16 (one block per batch), 256 threads.
__global__ __launch_bounds__(256) void chain_kernel(
    const float* __restrict__ ex, const float* __restrict__ eg,
    const float* __restrict__ gammap, float* __restrict__ M)
{
    __shared__ float A1[64][68];
    __shared__ float A2[64][68];
    __shared__ float red[64][4];

    const int b = blockIdx.x;
    const int tid = threadIdx.x;

    if (tid < 64) {
        const int c = tid;
        float r[64];
        // softmax of ex row -> A1
        #pragma unroll
        for (int d = 0; d < 64; ++d) r[d] = ex[b * 4096 + c * 64 + d];
        float mx = r[0];
        #pragma unroll
        for (int d = 1; d < 64; ++d) mx = fmaxf(mx, r[d]);
        float s = 0.f;
        #pragma unroll
        for (int d = 0; d < 64; ++d) { r[d] = expf(r[d] - mx); s += r[d]; }
        float inv = 1.f / s;
        #pragma unroll
        for (int d = 0; d < 64; ++d) A1[c][d] = r[d] * inv;
        // softmax of eg row -> A2
        #pragma unroll
        for (int d = 0; d < 64; ++d) r[d] = eg[b * 4096 + c * 64 + d];
        mx = r[0];
        #pragma unroll
        for (int d = 1; d < 64; ++d) mx = fmaxf(mx, r[d]);
        s = 0.f;
        #pragma unroll
        for (int d = 0; d < 64; ++d) { r[d] = expf(r[d] - mx); s += r[d]; }
        inv = 1.f / s;
        #pragma unroll
        for (int d = 0; d < 64; ++d) A2[c][d] = r[d] * inv;
    }
    __syncthreads();

    // GE[c][e] = sum_d A1[c][d] * A2[d][e]; thread owns (c, 16-col segment)
    const int c = tid >> 2, sq = tid & 3;
    float ge[16];
    #pragma unroll
    for (int k = 0; k < 16; ++k) ge[k] = 0.f;
    for (int d = 0; d < 64; ++d) {
        float a = A1[c][d];
        const float* row = &A2[d][sq * 16];
        #pragma unroll
        for (int k = 0; k < 16; ++k) ge[k] = fmaf(a, row[k], ge[k]);
    }

    // row max of GE
    float mx = ge[0];
    #pragma unroll
    for (int k = 1; k < 16; ++k) mx = fmaxf(mx, ge[k]);
    red[c][sq] = mx;
    __syncthreads();
    float gm = fmaxf(fmaxf(red[c][0], red[c][1]), fmaxf(red[c][2], red[c][3]));
    __syncthreads();

    // GEN = gm - GE; softmax(GEN)
    float gen[16];
    #pragma unroll
    for (int k = 0; k < 16; ++k) gen[k] = gm - ge[k];
    float mx2 = gen[0];
    #pragma unroll
    for (int k = 1; k < 16; ++k) mx2 = fmaxf(mx2, gen[k]);
    red[c][sq] = mx2;
    __syncthreads();
    float m2 = fmaxf(fmaxf(red[c][0], red[c][1]), fmaxf(red[c][2], red[c][3]));
    __syncthreads();

    float p[16];
    float s = 0.f;
    #pragma unroll
    for (int k = 0; k < 16; ++k) { p[k] = expf(gen[k] - m2); s += p[k]; }
    red[c][sq] = s;
    __syncthreads();
    float S = red[c][0] + red[c][1] + red[c][2] + red[c][3];

    float gam = gammap[0];
    float invS = 1.f / S;
    #pragma unroll
    for (int k = 0; k < 16; ++k) {
        int e = sq * 16 + k;
        M[b * 4096 + c * 64 + e] = gam * p[k] * invS + (e == c ? 1.f : 0.f);
    }
}

// ---- Kernel C: out[b] = M[b] @ x[b] --------------------------------------
// grid (256, 16), 256 threads; thread owns one pixel column (64 in, 64 out).
__global__ __launch_bounds__(256, 4) void apply_kernel(
    const float* __restrict__ x, const float* __restrict__ M,
    float* __restrict__ out)
{
    const int b = blockIdx.y;
    const int n = blockIdx.x * 256 + threadIdx.x;
    const float* xb = x + (size_t)b * NC * NPIX + n;
    float* ob = out + (size_t)b * NC * NPIX + n;

    float xv[64];
    #pragma unroll
    for (int d = 0; d < 64; ++d) xv[d] = xb[(size_t)d * NPIX];

    const float* Mb = M + b * 4096;   // block-uniform -> s_load expected
    for (int c = 0; c < 64; ++c) {
        const f4* Mr = (const f4*)(Mb + c * 64);
        float a0 = 0.f, a1 = 0.f, a2 = 0.f, a3 = 0.f;
        #pragma unroll
        for (int k = 0; k < 16; ++k) {
            f4 mv = Mr[k];
            a0 = fmaf(mv.x, xv[4 * k + 0], a0);
            a1 = fmaf(mv.y, xv[4 * k + 1], a1);
            a2 = fmaf(mv.z, xv[4 * k + 2], a2);
            a3 = fmaf(mv.w, xv[4 * k + 3], a3);
        }
        ob[(size_t)c * NPIX] = (a0 + a1) + (a2 + a3);
    }
}

extern "C" void kernel_launch(void* const* d_in, const int* in_sizes, int n_in,
                              void* d_out, int out_size, void* d_ws, size_t ws_size,
                              hipStream_t stream) {
    const float* x     = (const float*)d_in[0];
    const float* g     = (const float*)d_in[1];
    const float* gamma = (const float*)d_in[2];
    float* out = (float*)d_out;
    float* ws  = (float*)d_ws;

    float* ex = ws;                  // 16*4096 floats
    float* eg = ws + NB * 4096;      // 16*4096 floats
    float* M  = ws + 2 * NB * 4096;  // 16*4096 floats

    (void)hipMemsetAsync(ex, 0, 2 * NB * 4096 * sizeof(float), stream);
    gram_kernel<<<dim3(NPIX / GRAM_CHUNK, NB), 256, 0, stream>>>(x, g, ex, eg);
    chain_kernel<<<NB, 256, 0, stream>>>(ex, eg, gamma, M);
    apply_kernel<<<dim3(NPIX / 256, NB), 256, 0, stream>>>(x, M, out);
}

// Round 3
// 349.095 us; speedup vs baseline: 2.1414x; 2.1414x over previous
//
#include <hip/hip_runtime.h>

// ---------------------------------------------------------------------------
// G_CAM_Module: out = gamma * (GA @ x) + x, where GA comes from a chain of
// softmaxed 64x64 Gram matrices of x and g.
//
//   A) gram_kernel  : per-chunk partial Grams of x and g via MFMA f16
//                     (plain stores to scratch — NO atomics)
//   B) reduce_kernel: sum 64 chunk-partials -> ex[b], eg[b]
//   C) chain_kernel : softmax chain -> M = gamma*GA + I          (tiny, fp32)
//   D) apply_kernel : out[b] = M[b] @ x_b  (M staged in LDS, fp32 FMA)
// ---------------------------------------------------------------------------

typedef _Float16 h8 __attribute__((ext_vector_type(8)));
typedef float    f4 __attribute__((ext_vector_type(4)));
typedef __fp16   p2 __attribute__((ext_vector_type(2)));   // cvt_pkrtz result

#define NB 16
#define NC 64
#define NPIX 65536
#define GRAM_CHUNK 1024                 // pixels per gram block
#define PASS_PX 128                     // pixels per LDS pass
#define NPASS (GRAM_CHUNK / PASS_PX)    // 8
#define NCHUNK (NPIX / GRAM_CHUNK)      // 64
#define ROW_H 136                       // halves per LDS row (128 data + 8 pad)
#define LDS_H (64 * ROW_H + 64)         // halves per matrix (incl. row-group pads)

__device__ __forceinline__ int rowbase_h(int c) {
    // +16B gap every 8 rows keeps the 16-row fragment reads at <=2-way banks.
    return c * ROW_H + (c >> 3) * 8;
}

__device__ __forceinline__ unsigned int pk(float a, float b) {
    p2 v = __builtin_amdgcn_cvt_pkrtz(a, b);
    return __builtin_bit_cast(unsigned int, v);
}

// ---- Kernel A: partial Gram matrices via MFMA -----------------------------
// grid (64, 16), 512 threads = 8 waves. Waves 0-3: x-gram row-blocks 0-3;
// waves 4-7: g-gram. Each wave computes a 16x64 slice of the 64x64 Gram.
__global__ __launch_bounds__(512, 4) void gram_kernel(
    const float* __restrict__ x, const float* __restrict__ g,
    float* __restrict__ part)
{
    __shared__ __align__(16) _Float16 lds[2 * LDS_H];
    _Float16* xs = lds;
    _Float16* gs = lds + LDS_H;

    const int tid = threadIdx.x;
    const int b = blockIdx.y;
    const size_t cbase = (size_t)b * NC * NPIX + (size_t)blockIdx.x * GRAM_CHUNK;

    const int w     = tid >> 6;
    const int lane  = tid & 63;
    const int mtx   = w >> 2;         // 0: x, 1: g
    const int rb    = w & 3;          // C row-block (16 rows)
    const int l15   = lane & 15;
    const int khalf = lane >> 4;      // 0..3 -> which 8-elem k-group
    const _Float16* mybuf = mtx ? gs : xs;

    const int abase_h = rowbase_h(rb * 16 + l15);

    f4 acc[4];
    #pragma unroll
    for (int cb = 0; cb < 4; ++cb) acc[cb] = (f4){0.f, 0.f, 0.f, 0.f};

    for (int pass = 0; pass < NPASS; ++pass) {
        const size_t pbase = cbase + (size_t)pass * PASS_PX;
        // ---- stage 64ch x 128px of x and g into LDS as f16 ----
        #pragma unroll
        for (int it = 0; it < 4; ++it) {
            int e = it * 512 + tid;       // 0..2047
            int c = e >> 5;               // channel
            int q = e & 31;               // float4 index within 128 px
            f4 vx = *(const f4*)(x + pbase + (size_t)c * NPIX + q * 4);
            f4 vg = *(const f4*)(g + pbase + (size_t)c * NPIX + q * 4);
            unsigned long long hx =
                (unsigned long long)pk(vx.x, vx.y) | ((unsigned long long)pk(vx.z, vx.w) << 32);
            unsigned long long hg =
                (unsigned long long)pk(vg.x, vg.y) | ((unsigned long long)pk(vg.z, vg.w) << 32);
            int off = rowbase_h(c) + q * 4;
            *reinterpret_cast<unsigned long long*>(&xs[off]) = hx;
            *reinterpret_cast<unsigned long long*>(&gs[off]) = hg;
        }
        __syncthreads();

        // ---- 4 k-steps of K=32: 1 A-frag + 4 B-frags + 4 MFMAs ----
        #pragma unroll
        for (int ks = 0; ks < 4; ++ks) {
            int koff = ks * 32 + khalf * 8;   // halves into the row
            h8 a = *reinterpret_cast<const h8*>(&mybuf[abase_h + koff]);
            #pragma unroll
            for (int cb = 0; cb < 4; ++cb) {
                h8 bf = *reinterpret_cast<const h8*>(&mybuf[rowbase_h(cb * 16 + l15) + koff]);
                acc[cb] = __builtin_amdgcn_mfma_f32_16x16x32_f16(a, bf, acc[cb], 0, 0, 0);
            }
        }
        __syncthreads();
    }

    // plain stores of the 16x64 partial slice (no atomics)
    float* po = part + (((size_t)blockIdx.x * NB + b) * 2 + mtx) * 4096;
    #pragma unroll
    for (int cb = 0; cb < 4; ++cb)
        #pragma unroll
        for (int r = 0; r < 4; ++r)
            po[(rb * 16 + khalf * 4 + r) * 64 + cb * 16 + l15] = acc[cb][r];
}

// ---- Kernel B: reduce 64 chunk-partials -> ex, eg -------------------------
// grid 512 x 256 threads: one thread per output element (16*2*4096 = 131072).
__global__ __launch_bounds__(256) void reduce_kernel(
    const float* __restrict__ part, float* __restrict__ ex, float* __restrict__ eg)
{
    const int idx = blockIdx.x * 256 + threadIdx.x;
    const int bm = idx >> 12;          // b*2 + m
    const int cd = idx & 4095;
    float s = 0.f;
    #pragma unroll 8
    for (int ch = 0; ch < NCHUNK; ++ch)
        s += part[(size_t)ch * (NB * 2 * 4096) + (size_t)bm * 4096 + cd];
    float* dst = (bm & 1) ? eg : ex;
    dst[(bm >> 1) * 4096 + cd] = s;
}

// ---- Kernel C: softmax chain -> M = gamma*GA + I -------------------------
// grid 16 (one block per batch), 256 threads.
__global__ __launch_bounds__(256) void chain_kernel(
    const float* __restrict__ ex, const float* __restrict__ eg,
    const float* __restrict__ gammap, float* __restrict__ M)
{
    __shared__ float A1[64][68];
    __shared__ float A2[64][68];
    __shared__ float red[64][4];

    const int b = blockIdx.x;
    const int tid = threadIdx.x;

    if (tid < 64) {
        const int c = tid;
        float r[64];
        #pragma unroll
        for (int d = 0; d < 64; ++d) r[d] = ex[b * 4096 + c * 64 + d];
        float mx = r[0];
        #pragma unroll
        for (int d = 1; d < 64; ++d) mx = fmaxf(mx, r[d]);
        float s = 0.f;
        #pragma unroll
        for (int d = 0; d < 64; ++d) { r[d] = expf(r[d] - mx); s += r[d]; }
        float inv = 1.f / s;
        #pragma unroll
        for (int d = 0; d < 64; ++d) A1[c][d] = r[d] * inv;

        #pragma unroll
        for (int d = 0; d < 64; ++d) r[d] = eg[b * 4096 + c * 64 + d];
        mx = r[0];
        #pragma unroll
        for (int d = 1; d < 64; ++d) mx = fmaxf(mx, r[d]);
        s = 0.f;
        #pragma unroll
        for (int d = 0; d < 64; ++d) { r[d] = expf(r[d] - mx); s += r[d]; }
        inv = 1.f / s;
        #pragma unroll
        for (int d = 0; d < 64; ++d) A2[c][d] = r[d] * inv;
    }
    __syncthreads();

    // GE[c][e] = sum_d A1[c][d] * A2[d][e]; thread owns (c, 16-col segment)
    const int c = tid >> 2, sq = tid & 3;
    float ge[16];
    #pragma unroll
    for (int k = 0; k < 16; ++k) ge[k] = 0.f;
    for (int d = 0; d < 64; ++d) {
        float a = A1[c][d];
        const float* row = &A2[d][sq * 16];
        #pragma unroll
        for (int k = 0; k < 16; ++k) ge[k] = fmaf(a, row[k], ge[k]);
    }

    float mx = ge[0];
    #pragma unroll
    for (int k = 1; k < 16; ++k) mx = fmaxf(mx, ge[k]);
    red[c][sq] = mx;
    __syncthreads();
    float gm = fmaxf(fmaxf(red[c][0], red[c][1]), fmaxf(red[c][2], red[c][3]));
    __syncthreads();

    float gen[16];
    #pragma unroll
    for (int k = 0; k < 16; ++k) gen[k] = gm - ge[k];
    float mx2 = gen[0];
    #pragma unroll
    for (int k = 1; k < 16; ++k) mx2 = fmaxf(mx2, gen[k]);
    red[c][sq] = mx2;
    __syncthreads();
    float m2 = fmaxf(fmaxf(red[c][0], red[c][1]), fmaxf(red[c][2], red[c][3]));
    __syncthreads();

    float p[16];
    float s = 0.f;
    #pragma unroll
    for (int k = 0; k < 16; ++k) { p[k] = expf(gen[k] - m2); s += p[k]; }
    red[c][sq] = s;
    __syncthreads();
    float S = red[c][0] + red[c][1] + red[c][2] + red[c][3];

    float gam = gammap[0];
    float invS = 1.f / S;
    #pragma unroll
    for (int k = 0; k < 16; ++k) {
        int e = sq * 16 + k;
        M[b * 4096 + c * 64 + e] = gam * p[k] * invS + (e == c ? 1.f : 0.f);
    }
}

// ---- Kernel D: out[b] = M[b] @ x[b], M staged in LDS ----------------------
// grid (256, 16), 256 threads; thread owns one pixel column (64 in, 64 out).
__global__ __launch_bounds__(256, 4) void apply_kernel(
    const float* __restrict__ x, const float* __restrict__ M,
    float* __restrict__ out)
{
    __shared__ __align__(16) float Ml[4096];

    const int b = blockIdx.y;
    const int tid = threadIdx.x;
    const float* Mb = M + b * 4096;
    #pragma unroll
    for (int it = 0; it < 4; ++it)
        ((f4*)Ml)[it * 256 + tid] = ((const f4*)Mb)[it * 256 + tid];
    __syncthreads();

    const int n = blockIdx.x * 256 + tid;
    const float* xb = x + (size_t)b * NC * NPIX + n;
    float* ob = out + (size_t)b * NC * NPIX + n;

    float xv[64];
    #pragma unroll
    for (int d = 0; d < 64; ++d) xv[d] = xb[(size_t)d * NPIX];

    for (int c = 0; c < 64; ++c) {
        const f4* Mr = (const f4*)(Ml + c * 64);
        float a0 = 0.f, a1 = 0.f, a2 = 0.f, a3 = 0.f;
        #pragma unroll
        for (int k = 0; k < 16; ++k) {
            f4 mv = Mr[k];
            a0 = fmaf(mv.x, xv[4 * k + 0], a0);
            a1 = fmaf(mv.y, xv[4 * k + 1], a1);
            a2 = fmaf(mv.z, xv[4 * k + 2], a2);
            a3 = fmaf(mv.w, xv[4 * k + 3], a3);
        }
        ob[(size_t)c * NPIX] = (a0 + a1) + (a2 + a3);
    }
}

extern "C" void kernel_launch(void* const* d_in, const int* in_sizes, int n_in,
                              void* d_out, int out_size, void* d_ws, size_t ws_size,
                              hipStream_t stream) {
    const float* x     = (const float*)d_in[0];
    const float* g     = (const float*)d_in[1];
    const float* gamma = (const float*)d_in[2];
    float* out = (float*)d_out;
    float* ws  = (float*)d_ws;

    float* ex = ws;                  // 16*4096 floats
    float* eg = ws + NB * 4096;      // 16*4096 floats
    float* M  = ws + 2 * NB * 4096;  // 16*4096 floats

    // d_out doubles as scratch for the 33.5 MB gram partials; apply_kernel
    // fully overwrites d_out afterwards (stream-ordered), so this is safe.
    float* part = out;

    gram_kernel<<<dim3(NCHUNK, NB), 512, 0, stream>>>(x, g, part);
    reduce_kernel<<<512, 256, 0, stream>>>(part, ex, eg);
    chain_kernel<<<NB, 256, 0, stream>>>(ex, eg, gamma, M);
    apply_kernel<<<dim3(NPIX / 256, NB), 256, 0, stream>>>(x, M, out);
}